// Round 3
// baseline (146.846 us; speedup 1.0000x reference)
//
#include <hip/hip_runtime.h>

// TwelveSitesNN2 R14: layer 1 moved from VALU (324 inst/thread) to MFMA.
//  - prep builds WBT: circulant-expanded w1, [row=(s,o) 384][k=2*s'+c 24] f16,
//    so h1[b][s][o] = relu( sum_k WBT[(s,o)][k] * X[b][k] ), X = zs row (24 f).
//  - fused L1: swapped-operand MFMA (A=WBT rows from global/L2, B=x cols,
//    N=16=BT), 6 MFMA/wave; epilogue writes h1 rows as b64 pairs.
//  - layer 2 / pool / fc: R11's proven BT16 body, B-frags from LDS (R13 style).
//  - LDS 28672 B (w2T @0, h1 @3328dw); __launch_bounds__(256,4) -> no spills.

#define LNUM 63
#define BT 16
#define NBT 128   // 2048 / BT
#define WSL 29184 // ushorts per l: [w2T 6656][fw1T 8704][fw2T 4608][WBT 9216]

typedef __attribute__((ext_vector_type(8))) _Float16 half8;
typedef __attribute__((ext_vector_type(2))) _Float16 half2v;
typedef __attribute__((ext_vector_type(4))) float floatx4;
typedef __attribute__((ext_vector_type(4))) unsigned uint4v;

static __device__ __forceinline__ unsigned cvtpk(float a, float b) {
    return __builtin_bit_cast(unsigned, __builtin_amdgcn_cvt_pkrtz(a, b));  // 1 VALU op
}
static __device__ __forceinline__ half2v u2h(unsigned u) { return __builtin_bit_cast(half2v, u); }
static __device__ __forceinline__ float hlo16(unsigned short s) {
    return (float)__builtin_bit_cast(_Float16, s);
}
static __device__ __forceinline__ int w12(int v) { return v >= 12 ? v - 12 : v; }

// LDS layout of fused_nn, dword units (U: 7168 dw = 28672 B):
//   phase1/2 : w2T [o=64][52 dw] f16                                     @0
//              h1 [192 rows=(b*12+s)][20 dw] (16 used = 32 f16 ch)       @3328
//   phase2b  : PART [1024 u=(b*64+ch)][3 chunks] (f16 sum,max per dword)  @0 (overlay w2T)
//              POOLED [16 b][68 dw] (k'-interleaved mean/max f16)         @3072
//   phase3   : POOL2 ush@0 [16][72], G2 ush@1280 [16][72] (overlay PART)
#define O_H1     3328
#define O_POOLDW 3072
#define O_POOLUS 6144
#define O_POOL2  0
#define O_G2     1280

// prep: grid (LNUM, 4). r=0: w2T [o][52dw]; r=1: fw1T [o][68dw] k'-interleaved;
// r=2: fw2T [o][36dw]; r=3: WBT circulant-expanded w1 [384 rows][12 dw].
__global__ void prep(const float* __restrict__ w2, const float* __restrict__ fw1,
                     const float* __restrict__ fw2, const float* __restrict__ w1,
                     unsigned short* __restrict__ ws) {
    __shared__ float S[8192];
    const int l = blockIdx.x, r = blockIdx.y, t = threadIdx.x;
    if (r == 0) {
        const float4* src = (const float4*)(w2 + (size_t)l * 6144);   // [96][64]
        #pragma unroll
        for (int j = 0; j < 6; ++j) *(float4*)(S + 4 * (t + 256 * j)) = src[t + 256 * j];
        __syncthreads();
        unsigned* dst = (unsigned*)(ws + (size_t)l * WSL);            // 3328 dw
        #pragma unroll
        for (int j = 0; j < 13; ++j) {
            int i = j * 256 + t, o = i / 52, cp = i - 52 * o, c = 2 * cp;
            dst[i] = cvtpk(S[c * 64 + o], S[c * 64 + 64 + o]);
        }
    } else if (r == 1) {
        const float4* src = (const float4*)(fw1 + (size_t)l * 8192);  // [128][64]
        #pragma unroll
        for (int j = 0; j < 8; ++j) *(float4*)(S + 4 * (t + 256 * j)) = src[t + 256 * j];
        __syncthreads();
        unsigned* dst = (unsigned*)(ws + (size_t)l * WSL + 6656);     // 4352 dw
        #pragma unroll
        for (int j = 0; j < 17; ++j) {
            int i = j * 256 + t, o = i / 68, cp = i - 68 * o;
            dst[i] = cvtpk(S[cp * 64 + o], S[(64 + cp) * 64 + o]);    // k'-interleave
        }
    } else if (r == 2) {
        const float4* src = (const float4*)(fw2 + (size_t)l * 4096);  // [64][64]
        #pragma unroll
        for (int j = 0; j < 4; ++j) *(float4*)(S + 4 * (t + 256 * j)) = src[t + 256 * j];
        __syncthreads();
        unsigned* dst = (unsigned*)(ws + (size_t)l * WSL + 15360);    // 2304 dw
        #pragma unroll
        for (int j = 0; j < 9; ++j) {
            int i = j * 256 + t, o = i / 36, cp = i - 36 * o, c = 2 * cp;
            dst[i] = cvtpk(S[c * 64 + o], S[c * 64 + 64 + o]);
        }
    } else {
        // WBT: row = s*32+o (384), k' = site s' (12 dw); dword packs (c=0,c=1).
        // class(delta = (s'-s) mod 12): 0 -> w1 rows 0,1; {1,3,9,11} -> 2,3;
        // {2,4,8,10} -> 4,5; {5,6,7} -> zero.
        if (t < 192) S[t] = w1[(size_t)l * 192 + t];
        __syncthreads();
        unsigned* dst = (unsigned*)(ws + (size_t)l * WSL + 19968);    // 4608 dw
        #pragma unroll
        for (int j = 0; j < 18; ++j) {
            int i = j * 256 + t;               // 0..4607
            int row = i / 12, kp = i - 12 * row;
            int s = row >> 5, o = row & 31;
            int d = kp - s; if (d < 0) d += 12;
            unsigned v = 0;
            if (d == 0)                                    v = cvtpk(S[o],       S[32 + o]);
            else if (d == 1 || d == 3 || d == 9 || d == 11) v = cvtpk(S[64 + o],  S[96 + o]);
            else if (d == 2 || d == 4 || d == 8 || d == 10) v = cvtpk(S[128 + o], S[160 + o]);
            dst[i] = v;
        }
    }
}

__global__ __launch_bounds__(256, 4) void fused_nn(
    const float* __restrict__ zs,  const float* __restrict__ w1,
    const float* __restrict__ fb1, const float* __restrict__ fb2,
    const float* __restrict__ fw3, const float* __restrict__ fb3,
    const unsigned short* __restrict__ ws,
    float* __restrict__ out)
{
    __shared__ __align__(16) unsigned U[7168];
    unsigned short* USH = (unsigned short*)U;

    const int t    = threadIdx.x;
    const int lane = t & 63;
    const int wv   = t >> 6;          // 0..3
    const int n    = lane & 15;
    const int quad = lane >> 4;
    const int l    = blockIdx.x / NBT;
    const int b0   = (blockIdx.x % NBT) * BT;

    // ---------------- stage w2T (13312 B) global -> LDS ----------------
    // 832 uint4 over 256 threads: 3 rounds + partial (t < 64).
    {
        const uint4v* src = (const uint4v*)(ws + (size_t)l * WSL);
        uint4v s0 = src[t];
        uint4v s1 = src[t + 256];
        uint4v s2 = src[t + 512];
        uint4v* dst = (uint4v*)U;
        if (t < 64) {
            uint4v s3 = src[t + 768];
            dst[t] = s0; dst[t + 256] = s1; dst[t + 512] = s2; dst[t + 768] = s3;
        } else {
            dst[t] = s0; dst[t + 256] = s1; dst[t + 512] = s2;
        }
    }

    // ---------------- layer 1 as MFMA: D[(s,o)][b] = WBT x X ----------------
    // B-frag: lane (n=col=b_local, quad=k-chunk): x[b][8q..8q+7] as f16; quad 3 = 0.
    half8 xb;
    {
        uint4v z = {0u, 0u, 0u, 0u};
        if (quad < 3) {
            const float* xr = zs + ((size_t)(b0 + n) * LNUM + l) * 24 + quad * 8;
            float4 x0 = *(const float4*)(xr);
            float4 x1 = *(const float4*)(xr + 4);
            z.x = cvtpk(x0.x, x0.y); z.y = cvtpk(x0.z, x0.w);
            z.z = cvtpk(x1.x, x1.y); z.w = cvtpk(x1.z, x1.w);
        }
        xb = __builtin_bit_cast(half8, z);
    }
    {
        // A-frags direct from global (L2-hot): WBT row rt*16+n, k-chunk quad.
        const uint4v* wbt = (const uint4v*)(ws + (size_t)l * WSL + 19968);
        #pragma unroll
        for (int i = 0; i < 6; ++i) {
            const int rt = 6 * wv + i;            // row-tile; s = rt>>1, o-half = rt&1
            uint4v au = {0u, 0u, 0u, 0u};
            if (quad < 3) au = wbt[(rt * 16 + n) * 3 + quad];
            floatx4 c = __builtin_amdgcn_mfma_f32_16x16x32_f16(
                __builtin_bit_cast(half8, au), xb, (floatx4){0.f, 0.f, 0.f, 0.f}, 0, 0, 0);
            // D: col n = b_local, rows 4*quad+r -> o = (rt&1)*16 + 4*quad + r
            unsigned pk0 = cvtpk(fmaxf(c[0], 0.f), fmaxf(c[1], 0.f));
            unsigned pk1 = cvtpk(fmaxf(c[2], 0.f), fmaxf(c[3], 0.f));
            const int s = rt >> 1;
            const int dwoff = (rt & 1) * 8 + 2 * quad;
            *(uint2*)(U + O_H1 + (n * 12 + s) * 20 + dwoff) = make_uint2(pk0, pk1);
        }
    }
    // hoist fc bias loads (hide VMEM latency behind layer 2)
    const float bias1 = fb1[(size_t)l * 64 + wv * 16 + n];
    const float bias2 = fb2[(size_t)l * 64 + wv * 16 + n];
    __syncthreads();   // h1 ready AND w2T staged

    // ---------------- layer 2: MFMA f16 (M=192,K=96,N=64); add-tree A, B from LDS --
    floatx4 acc[3][4];
    #pragma unroll
    for (int mi = 0; mi < 3; ++mi)
        #pragma unroll
        for (int nt = 0; nt < 4; ++nt) acc[mi][nt] = (floatx4){0.f, 0.f, 0.f, 0.f};
    {
        int rb_[3], si_[3];
        #pragma unroll
        for (int mi = 0; mi < 3; ++mi) {
            int row = 48 * wv + 16 * mi + n;
            int bi = row / 12;
            si_[mi] = row - 12 * bi;
            rb_[mi] = bi * 12;
        }
        const uint4v* w2l = (const uint4v*)U;
        const int c13 = n * 13 + quad;         // per-lane uint4 base within a row
        const int q4 = quad * 4;
        const int dA[4] = {1, 11, 3, 9};
        const int dB[4] = {2, 10, 4, 8};
        #pragma unroll
        for (int ks = 0; ks < 3; ++ks) {
            uint4v bw[4];
            #pragma unroll
            for (int nt = 0; nt < 4; ++nt)
                bw[nt] = w2l[c13 + nt * 208 + ks * 4];
            half8 af[3];
            #pragma unroll
            for (int mi = 0; mi < 3; ++mi) {
                const int rb = rb_[mi], s = si_[mi];
                if (ks == 0) {
                    af[mi] = *(const half8*)(U + O_H1 + (rb + s) * 20 + q4);
                } else {
                    const int* d = (ks == 1) ? dA : dB;
                    half8 l0 = *(const half8*)(U + O_H1 + (rb + w12(s + d[0])) * 20 + q4);
                    half8 l1 = *(const half8*)(U + O_H1 + (rb + w12(s + d[1])) * 20 + q4);
                    half8 l2 = *(const half8*)(U + O_H1 + (rb + w12(s + d[2])) * 20 + q4);
                    half8 l3 = *(const half8*)(U + O_H1 + (rb + w12(s + d[3])) * 20 + q4);
                    af[mi] = (l0 + l1) + (l2 + l3);
                }
            }
            #pragma unroll
            for (int mi = 0; mi < 3; ++mi)
                #pragma unroll
                for (int nt = 0; nt < 4; ++nt)
                    acc[mi][nt] = __builtin_amdgcn_mfma_f32_16x16x32_f16(
                        af[mi], __builtin_bit_cast(half8, bw[nt]), acc[mi][nt], 0, 0, 0);
        }
    }
    __syncthreads();   // h1 + w2T reads done -> PART/POOLED overlays

    // ---------------- register pool partials: relu + sum4/max4 -> PART ----------------
    #pragma unroll
    for (int mi = 0; mi < 3; ++mi) {
        const int rr = 48 * wv + 16 * mi + 4 * quad;   // 4 rows, all within one b
        const int bq = rr / 12;
        const int chk = (rr - 12 * bq) >> 2;
        #pragma unroll
        for (int nt = 0; nt < 4; ++nt) {
            const int ch = nt * 16 + n;
            float r0 = fmaxf(acc[mi][nt][0], 0.f), r1 = fmaxf(acc[mi][nt][1], 0.f);
            float r2 = fmaxf(acc[mi][nt][2], 0.f), r3 = fmaxf(acc[mi][nt][3], 0.f);
            float sm = (r0 + r1) + (r2 + r3);
            float mx = fmaxf(fmaxf(r0, r1), fmaxf(r2, r3));
            U[(bq * 64 + ch) * 3 + chk] = cvtpk(sm, mx);
        }
    }
    // PART write->read is intra-wave (writer bq-range [4wv,4wv+3] == reader b = t>>4):
    // DS ops complete in order per wave; only prevent compiler reordering.
    __builtin_amdgcn_wave_barrier();

    // ---------------- pool-final: 3 b128 reads, f16 combine -> POOLED ----------------
    {
        const unsigned* p = U + t * 12;                // units 4t..4t+3
        uint4v q0 = *(const uint4v*)(p);
        uint4v q1 = *(const uint4v*)(p + 4);
        uint4v q2 = *(const uint4v*)(p + 8);
        unsigned arr[12] = {q0.x, q0.y, q0.z, q0.w, q1.x, q1.y, q1.z, q1.w,
                            q2.x, q2.y, q2.z, q2.w};
        const int b = t >> 4, ch0 = (t * 4) & 63;
        const _Float16 inv12 = (_Float16)(1.0f / 12.0f);
        unsigned pk[4];
        #pragma unroll
        for (int j = 0; j < 4; ++j) {
            half2v d0 = u2h(arr[3 * j]), d1 = u2h(arr[3 * j + 1]), d2 = u2h(arr[3 * j + 2]);
            _Float16 s = (d0[0] + d1[0]) + d2[0];
            _Float16 m0 = d0[1] > d1[1] ? d0[1] : d1[1];
            _Float16 m  = m0 > d2[1] ? m0 : d2[1];
            half2v pm;
            pm[0] = s * inv12;
            pm[1] = m;
            pk[j] = __builtin_bit_cast(unsigned, pm);
        }
        uint2 w01 = make_uint2(pk[0], pk[1]), w23 = make_uint2(pk[2], pk[3]);
        *(uint2*)(U + O_POOLDW + b * 68 + ch0)     = w01;
        *(uint2*)(U + O_POOLDW + b * 68 + ch0 + 2) = w23;
    }
    __syncthreads();

    // ---------------- fc1: MFMA (M=16, K=128, N=64), B from ws (k'-reordered) ----------------
    {
        const int o = wv * 16 + n;
        floatx4 a1 = (floatx4){bias1, bias1, bias1, bias1};
        const uint4v* f1q = (const uint4v*)(ws + (size_t)l * WSL + 6656);
        #pragma unroll
        for (int ks = 0; ks < 4; ++ks) {
            half8 av = *(const half8*)(USH + O_POOLUS + n * 136 + ks * 32 + quad * 8);
            uint4v bw = f1q[o * 17 + ks * 4 + quad];
            a1 = __builtin_amdgcn_mfma_f32_16x16x32_f16(av, __builtin_bit_cast(half8, bw), a1, 0, 0, 0);
        }
        #pragma unroll
        for (int i = 0; i < 2; ++i) {
            unsigned pk = cvtpk(fmaxf(a1[2 * i], 0.f), fmaxf(a1[2 * i + 1], 0.f));
            USH[O_POOL2 + (quad * 4 + 2 * i)     * 72 + o] = (unsigned short)(pk & 0xffffu);
            USH[O_POOL2 + (quad * 4 + 2 * i + 1) * 72 + o] = (unsigned short)(pk >> 16);
        }
    }
    __syncthreads();

    // ---------------- fc2: MFMA (M=16, K=64, N=64), B from ws ----------------
    {
        const int o = wv * 16 + n;
        floatx4 a2 = (floatx4){bias2, bias2, bias2, bias2};
        const uint4v* f2q = (const uint4v*)(ws + (size_t)l * WSL + 15360);
        #pragma unroll
        for (int ks = 0; ks < 2; ++ks) {
            half8 av = *(const half8*)(USH + O_POOL2 + n * 72 + ks * 32 + quad * 8);
            uint4v bw = f2q[o * 9 + ks * 4 + quad];
            a2 = __builtin_amdgcn_mfma_f32_16x16x32_f16(av, __builtin_bit_cast(half8, bw), a2, 0, 0, 0);
        }
        #pragma unroll
        for (int i = 0; i < 2; ++i) {
            unsigned pk = cvtpk(fmaxf(a2[2 * i], 0.f), fmaxf(a2[2 * i + 1], 0.f));
            USH[O_G2 + (quad * 4 + 2 * i)     * 72 + o] = (unsigned short)(pk & 0xffffu);
            USH[O_G2 + (quad * 4 + 2 * i + 1) * 72 + o] = (unsigned short)(pk >> 16);
        }
    }
    __syncthreads();

    // ---------------- fc3 (K=64) + output ----------------
    if (t < 16) {
        float a = fb3[l];
        const float* w3 = fw3 + (size_t)l * 64;
        #pragma unroll
        for (int c4 = 0; c4 < 16; ++c4) {
            uint2 u2 = *(const uint2*)(USH + O_G2 + t * 72 + c4 * 4);
            float4 w = *(const float4*)(w3 + c4 * 4);
            a += hlo16((unsigned short)(u2.x & 0xffff)) * w.x
               + hlo16((unsigned short)(u2.x >> 16))    * w.y
               + hlo16((unsigned short)(u2.y & 0xffff)) * w.z
               + hlo16((unsigned short)(u2.y >> 16))    * w.w;
        }
        out[(size_t)(b0 + t) * LNUM + l] = a;
    }
}

extern "C" void kernel_launch(void* const* d_in, const int* in_sizes, int n_in,
                              void* d_out, int out_size, void* d_ws, size_t ws_size,
                              hipStream_t stream) {
    const float* zs  = (const float*)d_in[0];
    const float* w1  = (const float*)d_in[1];
    const float* w2  = (const float*)d_in[2];
    const float* fw1 = (const float*)d_in[3];
    const float* fb1 = (const float*)d_in[4];
    const float* fw2 = (const float*)d_in[5];
    const float* fb2 = (const float*)d_in[6];
    const float* fw3 = (const float*)d_in[7];
    const float* fb3 = (const float*)d_in[8];
    float* out = (float*)d_out;
    unsigned short* ws = (unsigned short*)d_ws;

    hipLaunchKernelGGL(prep, dim3(LNUM, 4), dim3(256), 0, stream, w2, fw1, fw2, w1, ws);
    hipLaunchKernelGGL(fused_nn, dim3(LNUM * NBT), dim3(256), 0, stream,
                       zs, w1, fb1, fb2, fw3, fb3, ws, out);
}

// Round 4
// 146.725 us; speedup vs baseline: 1.0008x; 1.0008x over previous
//
#include <hip/hip_runtime.h>

// TwelveSitesNN2 R15: R14 (MFMA layer 1) + bank-conflict fix on h1 writes.
//  - R14 regression root-cause: L1 epilogue uint2 stores at lane stride 240 dw
//    (16 mod 32) -> 8 distinct banks -> 8-way conflict, +7M conflict-cycles.
//  - Fix: XOR the 16B-chunk index of each h1 row by (b & 3), b = batch row.
//    Writer banks become all-32-covered (2 accesses/bank = free); layer-2
//    readers apply the same XOR (key = bi&3, constant across a row-group's
//    9 taps since they share rb).
//  - Everything else identical to R14.

#define LNUM 63
#define BT 16
#define NBT 128   // 2048 / BT
#define WSL 29184 // ushorts per l: [w2T 6656][fw1T 8704][fw2T 4608][WBT 9216]

typedef __attribute__((ext_vector_type(8))) _Float16 half8;
typedef __attribute__((ext_vector_type(2))) _Float16 half2v;
typedef __attribute__((ext_vector_type(4))) float floatx4;
typedef __attribute__((ext_vector_type(4))) unsigned uint4v;

static __device__ __forceinline__ unsigned cvtpk(float a, float b) {
    return __builtin_bit_cast(unsigned, __builtin_amdgcn_cvt_pkrtz(a, b));  // 1 VALU op
}
static __device__ __forceinline__ half2v u2h(unsigned u) { return __builtin_bit_cast(half2v, u); }
static __device__ __forceinline__ float hlo16(unsigned short s) {
    return (float)__builtin_bit_cast(_Float16, s);
}
static __device__ __forceinline__ int w12(int v) { return v >= 12 ? v - 12 : v; }

// LDS layout of fused_nn, dword units (U: 7168 dw = 28672 B):
//   phase1/2 : w2T [o=64][52 dw] f16                                     @0
//              h1 [192 rows=(b*12+s)][20 dw] (16 used = 32 f16 ch;
//                 16B chunks XOR-permuted by (b&3))                      @3328
//   phase2b  : PART [1024 u=(b*64+ch)][3 chunks] (f16 sum,max per dword)  @0 (overlay w2T)
//              POOLED [16 b][68 dw] (k'-interleaved mean/max f16)         @3072
//   phase3   : POOL2 ush@0 [16][72], G2 ush@1280 [16][72] (overlay PART)
#define O_H1     3328
#define O_POOLDW 3072
#define O_POOLUS 6144
#define O_POOL2  0
#define O_G2     1280

// prep: grid (LNUM, 4). r=0: w2T [o][52dw]; r=1: fw1T [o][68dw] k'-interleaved;
// r=2: fw2T [o][36dw]; r=3: WBT circulant-expanded w1 [384 rows][12 dw].
__global__ void prep(const float* __restrict__ w2, const float* __restrict__ fw1,
                     const float* __restrict__ fw2, const float* __restrict__ w1,
                     unsigned short* __restrict__ ws) {
    __shared__ float S[8192];
    const int l = blockIdx.x, r = blockIdx.y, t = threadIdx.x;
    if (r == 0) {
        const float4* src = (const float4*)(w2 + (size_t)l * 6144);   // [96][64]
        #pragma unroll
        for (int j = 0; j < 6; ++j) *(float4*)(S + 4 * (t + 256 * j)) = src[t + 256 * j];
        __syncthreads();
        unsigned* dst = (unsigned*)(ws + (size_t)l * WSL);            // 3328 dw
        #pragma unroll
        for (int j = 0; j < 13; ++j) {
            int i = j * 256 + t, o = i / 52, cp = i - 52 * o, c = 2 * cp;
            dst[i] = cvtpk(S[c * 64 + o], S[c * 64 + 64 + o]);
        }
    } else if (r == 1) {
        const float4* src = (const float4*)(fw1 + (size_t)l * 8192);  // [128][64]
        #pragma unroll
        for (int j = 0; j < 8; ++j) *(float4*)(S + 4 * (t + 256 * j)) = src[t + 256 * j];
        __syncthreads();
        unsigned* dst = (unsigned*)(ws + (size_t)l * WSL + 6656);     // 4352 dw
        #pragma unroll
        for (int j = 0; j < 17; ++j) {
            int i = j * 256 + t, o = i / 68, cp = i - 68 * o;
            dst[i] = cvtpk(S[cp * 64 + o], S[(64 + cp) * 64 + o]);    // k'-interleave
        }
    } else if (r == 2) {
        const float4* src = (const float4*)(fw2 + (size_t)l * 4096);  // [64][64]
        #pragma unroll
        for (int j = 0; j < 4; ++j) *(float4*)(S + 4 * (t + 256 * j)) = src[t + 256 * j];
        __syncthreads();
        unsigned* dst = (unsigned*)(ws + (size_t)l * WSL + 15360);    // 2304 dw
        #pragma unroll
        for (int j = 0; j < 9; ++j) {
            int i = j * 256 + t, o = i / 36, cp = i - 36 * o, c = 2 * cp;
            dst[i] = cvtpk(S[c * 64 + o], S[c * 64 + 64 + o]);
        }
    } else {
        // WBT: row = s*32+o (384), k' = site s' (12 dw); dword packs (c=0,c=1).
        // class(delta = (s'-s) mod 12): 0 -> w1 rows 0,1; {1,3,9,11} -> 2,3;
        // {2,4,8,10} -> 4,5; {5,6,7} -> zero.
        if (t < 192) S[t] = w1[(size_t)l * 192 + t];
        __syncthreads();
        unsigned* dst = (unsigned*)(ws + (size_t)l * WSL + 19968);    // 4608 dw
        #pragma unroll
        for (int j = 0; j < 18; ++j) {
            int i = j * 256 + t;               // 0..4607
            int row = i / 12, kp = i - 12 * row;
            int s = row >> 5, o = row & 31;
            int d = kp - s; if (d < 0) d += 12;
            unsigned v = 0;
            if (d == 0)                                    v = cvtpk(S[o],       S[32 + o]);
            else if (d == 1 || d == 3 || d == 9 || d == 11) v = cvtpk(S[64 + o],  S[96 + o]);
            else if (d == 2 || d == 4 || d == 8 || d == 10) v = cvtpk(S[128 + o], S[160 + o]);
            dst[i] = v;
        }
    }
}

__global__ __launch_bounds__(256, 4) void fused_nn(
    const float* __restrict__ zs,  const float* __restrict__ w1,
    const float* __restrict__ fb1, const float* __restrict__ fb2,
    const float* __restrict__ fw3, const float* __restrict__ fb3,
    const unsigned short* __restrict__ ws,
    float* __restrict__ out)
{
    __shared__ __align__(16) unsigned U[7168];
    unsigned short* USH = (unsigned short*)U;

    const int t    = threadIdx.x;
    const int lane = t & 63;
    const int wv   = t >> 6;          // 0..3
    const int n    = lane & 15;
    const int quad = lane >> 4;
    const int l    = blockIdx.x / NBT;
    const int b0   = (blockIdx.x % NBT) * BT;

    // ---------------- stage w2T (13312 B) global -> LDS ----------------
    // 832 uint4 over 256 threads: 3 rounds + partial (t < 64).
    {
        const uint4v* src = (const uint4v*)(ws + (size_t)l * WSL);
        uint4v s0 = src[t];
        uint4v s1 = src[t + 256];
        uint4v s2 = src[t + 512];
        uint4v* dst = (uint4v*)U;
        if (t < 64) {
            uint4v s3 = src[t + 768];
            dst[t] = s0; dst[t + 256] = s1; dst[t + 512] = s2; dst[t + 768] = s3;
        } else {
            dst[t] = s0; dst[t + 256] = s1; dst[t + 512] = s2;
        }
    }

    // ---------------- layer 1 as MFMA: D[(s,o)][b] = WBT x X ----------------
    // B-frag: lane (n=col=b_local, quad=k-chunk): x[b][8q..8q+7] as f16; quad 3 = 0.
    half8 xb;
    {
        uint4v z = {0u, 0u, 0u, 0u};
        if (quad < 3) {
            const float* xr = zs + ((size_t)(b0 + n) * LNUM + l) * 24 + quad * 8;
            float4 x0 = *(const float4*)(xr);
            float4 x1 = *(const float4*)(xr + 4);
            z.x = cvtpk(x0.x, x0.y); z.y = cvtpk(x0.z, x0.w);
            z.z = cvtpk(x1.x, x1.y); z.w = cvtpk(x1.z, x1.w);
        }
        xb = __builtin_bit_cast(half8, z);
    }
    {
        // A-frags direct from global (L2-hot): WBT row rt*16+n, k-chunk quad.
        const uint4v* wbt = (const uint4v*)(ws + (size_t)l * WSL + 19968);
        #pragma unroll
        for (int i = 0; i < 6; ++i) {
            const int rt = 6 * wv + i;            // row-tile; s = rt>>1, o-half = rt&1
            uint4v au = {0u, 0u, 0u, 0u};
            if (quad < 3) au = wbt[(rt * 16 + n) * 3 + quad];
            floatx4 c = __builtin_amdgcn_mfma_f32_16x16x32_f16(
                __builtin_bit_cast(half8, au), xb, (floatx4){0.f, 0.f, 0.f, 0.f}, 0, 0, 0);
            // D: col n = b_local, rows 4*quad+r -> o = (rt&1)*16 + 4*quad + r
            unsigned pk0 = cvtpk(fmaxf(c[0], 0.f), fmaxf(c[1], 0.f));
            unsigned pk1 = cvtpk(fmaxf(c[2], 0.f), fmaxf(c[3], 0.f));
            const int s = rt >> 1;
            // chunk-XOR swizzle by (b&3): bank-spread the stores (R14 fix)
            const int chunk = (rt & 1) * 2 + (quad >> 1);
            const int dwoff = ((chunk ^ (n & 3)) << 2) | ((quad & 1) << 1);
            *(uint2*)(U + O_H1 + (n * 12 + s) * 20 + dwoff) = make_uint2(pk0, pk1);
        }
    }
    // hoist fc bias loads (hide VMEM latency behind layer 2)
    const float bias1 = fb1[(size_t)l * 64 + wv * 16 + n];
    const float bias2 = fb2[(size_t)l * 64 + wv * 16 + n];
    __syncthreads();   // h1 ready AND w2T staged

    // ---------------- layer 2: MFMA f16 (M=192,K=96,N=64); add-tree A, B from LDS --
    floatx4 acc[3][4];
    #pragma unroll
    for (int mi = 0; mi < 3; ++mi)
        #pragma unroll
        for (int nt = 0; nt < 4; ++nt) acc[mi][nt] = (floatx4){0.f, 0.f, 0.f, 0.f};
    {
        int rb_[3], si_[3], qx_[3];
        #pragma unroll
        for (int mi = 0; mi < 3; ++mi) {
            int row = 48 * wv + 16 * mi + n;
            int bi = row / 12;
            si_[mi] = row - 12 * bi;
            rb_[mi] = bi * 12;
            qx_[mi] = (quad ^ (bi & 3)) << 2;   // chunk-XOR key matches writer (b&3)
        }
        const uint4v* w2l = (const uint4v*)U;
        const int c13 = n * 13 + quad;         // per-lane uint4 base within a row
        const int dA[4] = {1, 11, 3, 9};
        const int dB[4] = {2, 10, 4, 8};
        #pragma unroll
        for (int ks = 0; ks < 3; ++ks) {
            uint4v bw[4];
            #pragma unroll
            for (int nt = 0; nt < 4; ++nt)
                bw[nt] = w2l[c13 + nt * 208 + ks * 4];
            half8 af[3];
            #pragma unroll
            for (int mi = 0; mi < 3; ++mi) {
                const int rb = rb_[mi], s = si_[mi], q4 = qx_[mi];
                if (ks == 0) {
                    af[mi] = *(const half8*)(U + O_H1 + (rb + s) * 20 + q4);
                } else {
                    const int* d = (ks == 1) ? dA : dB;
                    half8 l0 = *(const half8*)(U + O_H1 + (rb + w12(s + d[0])) * 20 + q4);
                    half8 l1 = *(const half8*)(U + O_H1 + (rb + w12(s + d[1])) * 20 + q4);
                    half8 l2 = *(const half8*)(U + O_H1 + (rb + w12(s + d[2])) * 20 + q4);
                    half8 l3 = *(const half8*)(U + O_H1 + (rb + w12(s + d[3])) * 20 + q4);
                    af[mi] = (l0 + l1) + (l2 + l3);
                }
            }
            #pragma unroll
            for (int mi = 0; mi < 3; ++mi)
                #pragma unroll
                for (int nt = 0; nt < 4; ++nt)
                    acc[mi][nt] = __builtin_amdgcn_mfma_f32_16x16x32_f16(
                        af[mi], __builtin_bit_cast(half8, bw[nt]), acc[mi][nt], 0, 0, 0);
        }
    }
    __syncthreads();   // h1 + w2T reads done -> PART/POOLED overlays

    // ---------------- register pool partials: relu + sum4/max4 -> PART ----------------
    #pragma unroll
    for (int mi = 0; mi < 3; ++mi) {
        const int rr = 48 * wv + 16 * mi + 4 * quad;   // 4 rows, all within one b
        const int bq = rr / 12;
        const int chk = (rr - 12 * bq) >> 2;
        #pragma unroll
        for (int nt = 0; nt < 4; ++nt) {
            const int ch = nt * 16 + n;
            float r0 = fmaxf(acc[mi][nt][0], 0.f), r1 = fmaxf(acc[mi][nt][1], 0.f);
            float r2 = fmaxf(acc[mi][nt][2], 0.f), r3 = fmaxf(acc[mi][nt][3], 0.f);
            float sm = (r0 + r1) + (r2 + r3);
            float mx = fmaxf(fmaxf(r0, r1), fmaxf(r2, r3));
            U[(bq * 64 + ch) * 3 + chk] = cvtpk(sm, mx);
        }
    }
    // PART write->read is intra-wave (writer bq-range [4wv,4wv+3] == reader b = t>>4):
    // DS ops complete in order per wave; only prevent compiler reordering.
    __builtin_amdgcn_wave_barrier();

    // ---------------- pool-final: 3 b128 reads, f16 combine -> POOLED ----------------
    {
        const unsigned* p = U + t * 12;                // units 4t..4t+3
        uint4v q0 = *(const uint4v*)(p);
        uint4v q1 = *(const uint4v*)(p + 4);
        uint4v q2 = *(const uint4v*)(p + 8);
        unsigned arr[12] = {q0.x, q0.y, q0.z, q0.w, q1.x, q1.y, q1.z, q1.w,
                            q2.x, q2.y, q2.z, q2.w};
        const int b = t >> 4, ch0 = (t * 4) & 63;
        const _Float16 inv12 = (_Float16)(1.0f / 12.0f);
        unsigned pk[4];
        #pragma unroll
        for (int j = 0; j < 4; ++j) {
            half2v d0 = u2h(arr[3 * j]), d1 = u2h(arr[3 * j + 1]), d2 = u2h(arr[3 * j + 2]);
            _Float16 s = (d0[0] + d1[0]) + d2[0];
            _Float16 m0 = d0[1] > d1[1] ? d0[1] : d1[1];
            _Float16 m  = m0 > d2[1] ? m0 : d2[1];
            half2v pm;
            pm[0] = s * inv12;
            pm[1] = m;
            pk[j] = __builtin_bit_cast(unsigned, pm);
        }
        uint2 w01 = make_uint2(pk[0], pk[1]), w23 = make_uint2(pk[2], pk[3]);
        *(uint2*)(U + O_POOLDW + b * 68 + ch0)     = w01;
        *(uint2*)(U + O_POOLDW + b * 68 + ch0 + 2) = w23;
    }
    __syncthreads();

    // ---------------- fc1: MFMA (M=16, K=128, N=64), B from ws (k'-reordered) ----------------
    {
        const int o = wv * 16 + n;
        floatx4 a1 = (floatx4){bias1, bias1, bias1, bias1};
        const uint4v* f1q = (const uint4v*)(ws + (size_t)l * WSL + 6656);
        #pragma unroll
        for (int ks = 0; ks < 4; ++ks) {
            half8 av = *(const half8*)(USH + O_POOLUS + n * 136 + ks * 32 + quad * 8);
            uint4v bw = f1q[o * 17 + ks * 4 + quad];
            a1 = __builtin_amdgcn_mfma_f32_16x16x32_f16(av, __builtin_bit_cast(half8, bw), a1, 0, 0, 0);
        }
        #pragma unroll
        for (int i = 0; i < 2; ++i) {
            unsigned pk = cvtpk(fmaxf(a1[2 * i], 0.f), fmaxf(a1[2 * i + 1], 0.f));
            USH[O_POOL2 + (quad * 4 + 2 * i)     * 72 + o] = (unsigned short)(pk & 0xffffu);
            USH[O_POOL2 + (quad * 4 + 2 * i + 1) * 72 + o] = (unsigned short)(pk >> 16);
        }
    }
    __syncthreads();

    // ---------------- fc2: MFMA (M=16, K=64, N=64), B from ws ----------------
    {
        const int o = wv * 16 + n;
        floatx4 a2 = (floatx4){bias2, bias2, bias2, bias2};
        const uint4v* f2q = (const uint4v*)(ws + (size_t)l * WSL + 15360);
        #pragma unroll
        for (int ks = 0; ks < 2; ++ks) {
            half8 av = *(const half8*)(USH + O_POOL2 + n * 72 + ks * 32 + quad * 8);
            uint4v bw = f2q[o * 9 + ks * 4 + quad];
            a2 = __builtin_amdgcn_mfma_f32_16x16x32_f16(av, __builtin_bit_cast(half8, bw), a2, 0, 0, 0);
        }
        #pragma unroll
        for (int i = 0; i < 2; ++i) {
            unsigned pk = cvtpk(fmaxf(a2[2 * i], 0.f), fmaxf(a2[2 * i + 1], 0.f));
            USH[O_G2 + (quad * 4 + 2 * i)     * 72 + o] = (unsigned short)(pk & 0xffffu);
            USH[O_G2 + (quad * 4 + 2 * i + 1) * 72 + o] = (unsigned short)(pk >> 16);
        }
    }
    __syncthreads();

    // ---------------- fc3 (K=64) + output ----------------
    if (t < 16) {
        float a = fb3[l];
        const float* w3 = fw3 + (size_t)l * 64;
        #pragma unroll
        for (int c4 = 0; c4 < 16; ++c4) {
            uint2 u2 = *(const uint2*)(USH + O_G2 + t * 72 + c4 * 4);
            float4 w = *(const float4*)(w3 + c4 * 4);
            a += hlo16((unsigned short)(u2.x & 0xffff)) * w.x
               + hlo16((unsigned short)(u2.x >> 16))    * w.y
               + hlo16((unsigned short)(u2.y & 0xffff)) * w.z
               + hlo16((unsigned short)(u2.y >> 16))    * w.w;
        }
        out[(size_t)(b0 + t) * LNUM + l] = a;
    }
}

extern "C" void kernel_launch(void* const* d_in, const int* in_sizes, int n_in,
                              void* d_out, int out_size, void* d_ws, size_t ws_size,
                              hipStream_t stream) {
    const float* zs  = (const float*)d_in[0];
    const float* w1  = (const float*)d_in[1];
    const float* w2  = (const float*)d_in[2];
    const float* fw1 = (const float*)d_in[3];
    const float* fb1 = (const float*)d_in[4];
    const float* fw2 = (const float*)d_in[5];
    const float* fb2 = (const float*)d_in[6];
    const float* fw3 = (const float*)d_in[7];
    const float* fb3 = (const float*)d_in[8];
    float* out = (float*)d_out;
    unsigned short* ws = (unsigned short*)d_ws;

    hipLaunchKernelGGL(prep, dim3(LNUM, 4), dim3(256), 0, stream, w2, fw1, fw2, w1, ws);
    hipLaunchKernelGGL(fused_nn, dim3(LNUM * NBT), dim3(256), 0, stream,
                       zs, w1, fb1, fb2, fw3, fb3, ws, out);
}

// Round 5
// 137.319 us; speedup vs baseline: 1.0694x; 1.0685x over previous
//
#include <hip/hip_runtime.h>

// TwelveSitesNN2 R16: combine the proven halves of R11 and R14/R15.
//  - R11 body: h1 @0 (16.6KB LDS), layer-2 B-fragments in 48 prefetch VGPRs
//    (NO w2T LDS staging phase), PART/pool/fc1/fc2/fc3 unchanged.
//  - R14/R15 layer 1: MFMA over circulant-expanded WBT (A from global/L2,
//    B = x columns, N=16=BT), XOR-swizzled h1 chunk stores (b64 bank floor).
//  - Load order: zs -> WBT -> bwp so L1 MFMA isn't gated on bwp returns.
//  - __launch_bounds__(256,4); peak unified regs ~121 (bwp48+acc48+addr) -> no spill.

#define LNUM 63
#define BT 16
#define NBT 128   // 2048 / BT
#define WSL 29184 // ushorts per l: [w2T 6656][fw1T 8704][fw2T 4608][WBT 9216]

typedef __attribute__((ext_vector_type(8))) _Float16 half8;
typedef __attribute__((ext_vector_type(2))) _Float16 half2v;
typedef __attribute__((ext_vector_type(4))) float floatx4;
typedef __attribute__((ext_vector_type(4))) unsigned uint4v;

static __device__ __forceinline__ unsigned cvtpk(float a, float b) {
    return __builtin_bit_cast(unsigned, __builtin_amdgcn_cvt_pkrtz(a, b));  // 1 VALU op
}
static __device__ __forceinline__ half2v u2h(unsigned u) { return __builtin_bit_cast(half2v, u); }
static __device__ __forceinline__ float hlo16(unsigned short s) {
    return (float)__builtin_bit_cast(_Float16, s);
}
static __device__ __forceinline__ int w12(int v) { return v >= 12 ? v - 12 : v; }

// LDS layout of fused_nn, dword units (U: 4160 dw = 16640 B):
//   phase1 : h1 [192 rows=(b*12+s)][20 dw] (16 used = 32 f16 ch;
//            16B chunks XOR-permuted by (b&3))                            @0
//   phase2 : PART [1024 u=(b*64+ch)][3 chunks] (f16 sum,max per dword)    @0 (overlay)
//            POOLED [16 b][68 dw] (k'-interleaved mean/max f16)           @3072
//   phase3 : POOL2 ush@0 [16][72], G2 ush@1280 [16][72] (overlay PART)
#define O_POOLDW 3072
#define O_POOLUS 6144
#define O_POOL2  0
#define O_G2     1280

// prep: grid (LNUM, 4). r=0: w2T [o][52dw]; r=1: fw1T [o][68dw] k'-interleaved;
// r=2: fw2T [o][36dw]; r=3: WBT circulant-expanded w1 [384 rows][12 dw].
__global__ void prep(const float* __restrict__ w2, const float* __restrict__ fw1,
                     const float* __restrict__ fw2, const float* __restrict__ w1,
                     unsigned short* __restrict__ ws) {
    __shared__ float S[8192];
    const int l = blockIdx.x, r = blockIdx.y, t = threadIdx.x;
    if (r == 0) {
        const float4* src = (const float4*)(w2 + (size_t)l * 6144);   // [96][64]
        #pragma unroll
        for (int j = 0; j < 6; ++j) *(float4*)(S + 4 * (t + 256 * j)) = src[t + 256 * j];
        __syncthreads();
        unsigned* dst = (unsigned*)(ws + (size_t)l * WSL);            // 3328 dw
        #pragma unroll
        for (int j = 0; j < 13; ++j) {
            int i = j * 256 + t, o = i / 52, cp = i - 52 * o, c = 2 * cp;
            dst[i] = cvtpk(S[c * 64 + o], S[c * 64 + 64 + o]);
        }
    } else if (r == 1) {
        const float4* src = (const float4*)(fw1 + (size_t)l * 8192);  // [128][64]
        #pragma unroll
        for (int j = 0; j < 8; ++j) *(float4*)(S + 4 * (t + 256 * j)) = src[t + 256 * j];
        __syncthreads();
        unsigned* dst = (unsigned*)(ws + (size_t)l * WSL + 6656);     // 4352 dw
        #pragma unroll
        for (int j = 0; j < 17; ++j) {
            int i = j * 256 + t, o = i / 68, cp = i - 68 * o;
            dst[i] = cvtpk(S[cp * 64 + o], S[(64 + cp) * 64 + o]);    // k'-interleave
        }
    } else if (r == 2) {
        const float4* src = (const float4*)(fw2 + (size_t)l * 4096);  // [64][64]
        #pragma unroll
        for (int j = 0; j < 4; ++j) *(float4*)(S + 4 * (t + 256 * j)) = src[t + 256 * j];
        __syncthreads();
        unsigned* dst = (unsigned*)(ws + (size_t)l * WSL + 15360);    // 2304 dw
        #pragma unroll
        for (int j = 0; j < 9; ++j) {
            int i = j * 256 + t, o = i / 36, cp = i - 36 * o, c = 2 * cp;
            dst[i] = cvtpk(S[c * 64 + o], S[c * 64 + 64 + o]);
        }
    } else {
        // WBT: row = s*32+o (384), k' = site s' (12 dw); dword packs (c=0,c=1).
        // class(delta = (s'-s) mod 12): 0 -> w1 rows 0,1; {1,3,9,11} -> 2,3;
        // {2,4,8,10} -> 4,5; {5,6,7} -> zero.
        if (t < 192) S[t] = w1[(size_t)l * 192 + t];
        __syncthreads();
        unsigned* dst = (unsigned*)(ws + (size_t)l * WSL + 19968);    // 4608 dw
        #pragma unroll
        for (int j = 0; j < 18; ++j) {
            int i = j * 256 + t;               // 0..4607
            int row = i / 12, kp = i - 12 * row;
            int s = row >> 5, o = row & 31;
            int d = kp - s; if (d < 0) d += 12;
            unsigned v = 0;
            if (d == 0)                                    v = cvtpk(S[o],       S[32 + o]);
            else if (d == 1 || d == 3 || d == 9 || d == 11) v = cvtpk(S[64 + o],  S[96 + o]);
            else if (d == 2 || d == 4 || d == 8 || d == 10) v = cvtpk(S[128 + o], S[160 + o]);
            dst[i] = v;
        }
    }
}

__global__ __launch_bounds__(256, 4) void fused_nn(
    const float* __restrict__ zs,  const float* __restrict__ w1,
    const float* __restrict__ fb1, const float* __restrict__ fb2,
    const float* __restrict__ fw3, const float* __restrict__ fb3,
    const unsigned short* __restrict__ ws,
    float* __restrict__ out)
{
    __shared__ __align__(16) unsigned U[4160];
    unsigned short* USH = (unsigned short*)U;

    const int t    = threadIdx.x;
    const int lane = t & 63;
    const int wv   = t >> 6;          // 0..3
    const int n    = lane & 15;
    const int quad = lane >> 4;
    const int l    = blockIdx.x / NBT;
    const int b0   = (blockIdx.x % NBT) * BT;

    // ---------------- issue loads: zs -> WBT -> bwp (vmcnt FIFO friendly) ----------
    float4 x0 = {0.f, 0.f, 0.f, 0.f}, x1 = {0.f, 0.f, 0.f, 0.f};
    if (quad < 3) {
        const float* xr = zs + ((size_t)(b0 + n) * LNUM + l) * 24 + quad * 8;
        x0 = *(const float4*)(xr);
        x1 = *(const float4*)(xr + 4);
    }
    uint4v au[6];
    {
        const uint4v* wbt = (const uint4v*)(ws + (size_t)l * WSL + 19968);
        #pragma unroll
        for (int i = 0; i < 6; ++i) {
            const int rt = 6 * wv + i;
            au[i] = (quad < 3) ? wbt[(rt * 16 + n) * 3 + quad] : (uint4v){0u, 0u, 0u, 0u};
        }
    }
    // layer-2 B fragments: 48 VGPRs, latency hidden behind L1 + barrier (R11)
    uint4v bwp[3][4];
    {
        const uint4v* w2q = (const uint4v*)(ws + (size_t)l * WSL);
        #pragma unroll
        for (int ks = 0; ks < 3; ++ks)
            #pragma unroll
            for (int nt = 0; nt < 4; ++nt)
                bwp[ks][nt] = w2q[(nt * 16 + n) * 13 + ks * 4 + quad];
    }

    // ---------------- layer 1 as MFMA: D[(s,o)][b] = WBT x X ----------------
    half8 xb;
    {
        uint4v z = {0u, 0u, 0u, 0u};
        if (quad < 3) {
            z.x = cvtpk(x0.x, x0.y); z.y = cvtpk(x0.z, x0.w);
            z.z = cvtpk(x1.x, x1.y); z.w = cvtpk(x1.z, x1.w);
        }
        xb = __builtin_bit_cast(half8, z);
    }
    {
        #pragma unroll
        for (int i = 0; i < 6; ++i) {
            const int rt = 6 * wv + i;            // s = rt>>1, o-half = rt&1
            floatx4 c = __builtin_amdgcn_mfma_f32_16x16x32_f16(
                __builtin_bit_cast(half8, au[i]), xb, (floatx4){0.f, 0.f, 0.f, 0.f}, 0, 0, 0);
            unsigned pk0 = cvtpk(fmaxf(c[0], 0.f), fmaxf(c[1], 0.f));
            unsigned pk1 = cvtpk(fmaxf(c[2], 0.f), fmaxf(c[3], 0.f));
            const int s = rt >> 1;
            // chunk-XOR swizzle by (b&3): b64-store bank floor (R15)
            const int chunk = (rt & 1) * 2 + (quad >> 1);
            const int dwoff = ((chunk ^ (n & 3)) << 2) | ((quad & 1) << 1);
            *(uint2*)(U + (n * 12 + s) * 20 + dwoff) = make_uint2(pk0, pk1);
        }
    }
    // hoist fc bias loads (hide VMEM latency behind layer 2)
    const float bias1 = fb1[(size_t)l * 64 + wv * 16 + n];
    const float bias2 = fb2[(size_t)l * 64 + wv * 16 + n];
    __syncthreads();   // h1 ready

    // ---------------- layer 2: MFMA f16 (M=192,K=96,N=64); add-tree A, B from regs --
    floatx4 acc[3][4];
    #pragma unroll
    for (int mi = 0; mi < 3; ++mi)
        #pragma unroll
        for (int nt = 0; nt < 4; ++nt) acc[mi][nt] = (floatx4){0.f, 0.f, 0.f, 0.f};
    {
        int rb_[3], si_[3], qx_[3];
        #pragma unroll
        for (int mi = 0; mi < 3; ++mi) {
            int row = 48 * wv + 16 * mi + n;
            int bi = row / 12;
            si_[mi] = row - 12 * bi;
            rb_[mi] = bi * 12;
            qx_[mi] = (quad ^ (bi & 3)) << 2;   // chunk-XOR key matches writer (b&3)
        }
        const int dA[4] = {1, 11, 3, 9};
        const int dB[4] = {2, 10, 4, 8};
        #pragma unroll
        for (int ks = 0; ks < 3; ++ks) {
            half8 af[3];
            #pragma unroll
            for (int mi = 0; mi < 3; ++mi) {
                const int rb = rb_[mi], s = si_[mi], q4 = qx_[mi];
                if (ks == 0) {
                    af[mi] = *(const half8*)(U + (rb + s) * 20 + q4);
                } else {
                    const int* d = (ks == 1) ? dA : dB;
                    half8 l0 = *(const half8*)(U + (rb + w12(s + d[0])) * 20 + q4);
                    half8 l1 = *(const half8*)(U + (rb + w12(s + d[1])) * 20 + q4);
                    half8 l2 = *(const half8*)(U + (rb + w12(s + d[2])) * 20 + q4);
                    half8 l3 = *(const half8*)(U + (rb + w12(s + d[3])) * 20 + q4);
                    af[mi] = (l0 + l1) + (l2 + l3);
                }
            }
            #pragma unroll
            for (int mi = 0; mi < 3; ++mi)
                #pragma unroll
                for (int nt = 0; nt < 4; ++nt)
                    acc[mi][nt] = __builtin_amdgcn_mfma_f32_16x16x32_f16(
                        af[mi], __builtin_bit_cast(half8, bwp[ks][nt]), acc[mi][nt], 0, 0, 0);
        }
    }
    __syncthreads();   // h1 reads done -> PART overlays

    // ---------------- register pool partials: relu + sum4/max4 -> PART ----------------
    #pragma unroll
    for (int mi = 0; mi < 3; ++mi) {
        const int rr = 48 * wv + 16 * mi + 4 * quad;   // 4 rows, all within one b
        const int bq = rr / 12;
        const int chk = (rr - 12 * bq) >> 2;
        #pragma unroll
        for (int nt = 0; nt < 4; ++nt) {
            const int ch = nt * 16 + n;
            float r0 = fmaxf(acc[mi][nt][0], 0.f), r1 = fmaxf(acc[mi][nt][1], 0.f);
            float r2 = fmaxf(acc[mi][nt][2], 0.f), r3 = fmaxf(acc[mi][nt][3], 0.f);
            float sm = (r0 + r1) + (r2 + r3);
            float mx = fmaxf(fmaxf(r0, r1), fmaxf(r2, r3));
            U[(bq * 64 + ch) * 3 + chk] = cvtpk(sm, mx);
        }
    }
    // PART write->read is intra-wave (writer bq-range [4wv,4wv+3] == reader b = t>>4):
    // DS ops complete in order per wave; only prevent compiler reordering.
    __builtin_amdgcn_wave_barrier();

    // ---------------- pool-final: 3 b128 reads, f16 combine -> POOLED ----------------
    {
        const unsigned* p = U + t * 12;                // units 4t..4t+3
        uint4v q0 = *(const uint4v*)(p);
        uint4v q1 = *(const uint4v*)(p + 4);
        uint4v q2 = *(const uint4v*)(p + 8);
        unsigned arr[12] = {q0.x, q0.y, q0.z, q0.w, q1.x, q1.y, q1.z, q1.w,
                            q2.x, q2.y, q2.z, q2.w};
        const int b = t >> 4, ch0 = (t * 4) & 63;
        const _Float16 inv12 = (_Float16)(1.0f / 12.0f);
        unsigned pk[4];
        #pragma unroll
        for (int j = 0; j < 4; ++j) {
            half2v d0 = u2h(arr[3 * j]), d1 = u2h(arr[3 * j + 1]), d2 = u2h(arr[3 * j + 2]);
            _Float16 s = (d0[0] + d1[0]) + d2[0];
            _Float16 m0 = d0[1] > d1[1] ? d0[1] : d1[1];
            _Float16 m  = m0 > d2[1] ? m0 : d2[1];
            half2v pm;
            pm[0] = s * inv12;
            pm[1] = m;
            pk[j] = __builtin_bit_cast(unsigned, pm);
        }
        uint2 w01 = make_uint2(pk[0], pk[1]), w23 = make_uint2(pk[2], pk[3]);
        *(uint2*)(U + O_POOLDW + b * 68 + ch0)     = w01;
        *(uint2*)(U + O_POOLDW + b * 68 + ch0 + 2) = w23;
    }
    __syncthreads();

    // ---------------- fc1: MFMA (M=16, K=128, N=64), B from ws (k'-reordered) ----------------
    {
        const int o = wv * 16 + n;
        floatx4 a1 = (floatx4){bias1, bias1, bias1, bias1};
        const uint4v* f1q = (const uint4v*)(ws + (size_t)l * WSL + 6656);
        #pragma unroll
        for (int ks = 0; ks < 4; ++ks) {
            half8 av = *(const half8*)(USH + O_POOLUS + n * 136 + ks * 32 + quad * 8);
            uint4v bw = f1q[o * 17 + ks * 4 + quad];
            a1 = __builtin_amdgcn_mfma_f32_16x16x32_f16(av, __builtin_bit_cast(half8, bw), a1, 0, 0, 0);
        }
        #pragma unroll
        for (int i = 0; i < 2; ++i) {
            unsigned pk = cvtpk(fmaxf(a1[2 * i], 0.f), fmaxf(a1[2 * i + 1], 0.f));
            USH[O_POOL2 + (quad * 4 + 2 * i)     * 72 + o] = (unsigned short)(pk & 0xffffu);
            USH[O_POOL2 + (quad * 4 + 2 * i + 1) * 72 + o] = (unsigned short)(pk >> 16);
        }
    }
    __syncthreads();

    // ---------------- fc2: MFMA (M=16, K=64, N=64), B from ws ----------------
    {
        const int o = wv * 16 + n;
        floatx4 a2 = (floatx4){bias2, bias2, bias2, bias2};
        const uint4v* f2q = (const uint4v*)(ws + (size_t)l * WSL + 15360);
        #pragma unroll
        for (int ks = 0; ks < 2; ++ks) {
            half8 av = *(const half8*)(USH + O_POOL2 + n * 72 + ks * 32 + quad * 8);
            uint4v bw = f2q[o * 9 + ks * 4 + quad];
            a2 = __builtin_amdgcn_mfma_f32_16x16x32_f16(av, __builtin_bit_cast(half8, bw), a2, 0, 0, 0);
        }
        #pragma unroll
        for (int i = 0; i < 2; ++i) {
            unsigned pk = cvtpk(fmaxf(a2[2 * i], 0.f), fmaxf(a2[2 * i + 1], 0.f));
            USH[O_G2 + (quad * 4 + 2 * i)     * 72 + o] = (unsigned short)(pk & 0xffffu);
            USH[O_G2 + (quad * 4 + 2 * i + 1) * 72 + o] = (unsigned short)(pk >> 16);
        }
    }
    __syncthreads();

    // ---------------- fc3 (K=64) + output ----------------
    if (t < 16) {
        float a = fb3[l];
        const float* w3 = fw3 + (size_t)l * 64;
        #pragma unroll
        for (int c4 = 0; c4 < 16; ++c4) {
            uint2 u2 = *(const uint2*)(USH + O_G2 + t * 72 + c4 * 4);
            float4 w = *(const float4*)(w3 + c4 * 4);
            a += hlo16((unsigned short)(u2.x & 0xffff)) * w.x
               + hlo16((unsigned short)(u2.x >> 16))    * w.y
               + hlo16((unsigned short)(u2.y & 0xffff)) * w.z
               + hlo16((unsigned short)(u2.y >> 16))    * w.w;
        }
        out[(size_t)(b0 + t) * LNUM + l] = a;
    }
}

extern "C" void kernel_launch(void* const* d_in, const int* in_sizes, int n_in,
                              void* d_out, int out_size, void* d_ws, size_t ws_size,
                              hipStream_t stream) {
    const float* zs  = (const float*)d_in[0];
    const float* w1  = (const float*)d_in[1];
    const float* w2  = (const float*)d_in[2];
    const float* fw1 = (const float*)d_in[3];
    const float* fb1 = (const float*)d_in[4];
    const float* fw2 = (const float*)d_in[5];
    const float* fb2 = (const float*)d_in[6];
    const float* fw3 = (const float*)d_in[7];
    const float* fb3 = (const float*)d_in[8];
    float* out = (float*)d_out;
    unsigned short* ws = (unsigned short*)d_ws;

    hipLaunchKernelGGL(prep, dim3(LNUM, 4), dim3(256), 0, stream, w2, fw1, fw2, w1, ws);
    hipLaunchKernelGGL(fused_nn, dim3(LNUM * NBT), dim3(256), 0, stream,
                       zs, w1, fb1, fb2, fw3, fb3, ws, out);
}